// Round 10
// baseline (88.251 us; speedup 1.0000x reference)
//
#include <hip/hip_runtime.h>
#include <math.h>

#define HH 256
#define WW 256
#define NG 714
#define NROWS 768          // padded rows; pad rows always culled
#define NGP4 716           // s_tz padded for float4 rank loop
#define SEG 23             // rows per wave sub-segment (32 segs x 23 = 736 >= 714)
#define NQTR 8             // depth slices per tile (8 x 4 waves = 32 segments)
#define FOCALF 128.0f
#define EPS2D_F 0.3f
#define ALPHA_MIN_F (1.0f/255.0f)
#define CAM_T_F 8.0f
#define LOG2E_F 1.4426950408889634f
#define T_EPS 0.003f       // in-wave early-break bound (error <= eps per channel)
#define NPX 65536
// params layout: cull[NROWS] float4 = [mx,my,e/thr,f/thr]  (12 KB)
//                rows[NROWS*3] float4 = [mx,my,A2n,B2n][C2n,K,cr,cg][cb,-,-,-] (36 KB)

// Kernel 1: projection + conic + stable depth rank + scatter into sorted rows.
// Rank loop split 4-ways across a quad of lanes per row + __shfl_xor reduce
// (round-9 win). Conic NEGATED, prefolded with log2(e); K = log2(op) additive.
// Round-10: cull fields normalized by thr into a SEPARATE float4 array so the
// composite pre-pass needs ONE load instead of two. Cull iff
// max(e'*dymin^2, f'*dxmin^2) > 1 (exact box cull, same inequality scaled).
__global__ __launch_bounds__(1024) void gs_prep(
    const float* __restrict__ means, const float* __restrict__ quats,
    const float* __restrict__ scales, const float* __restrict__ opacities,
    const float* __restrict__ rgbs, float* __restrict__ params)
{
    __shared__ float s_tz[NGP4];
    const int tid = threadIdx.x;            // 0..1023
    const int sub = tid & 3;                // quad lane (rank chunk)
    const int i   = blockIdx.x * 256 + (tid >> 2);   // row 0..767

    for (int j = tid; j < NGP4; j += 1024)
        s_tz[j] = (j < NG) ? (means[3*j+2] + CAM_T_F) : INFINITY;
    __syncthreads();

    float4* cullw = (float4*)params;
    float4* rowsw = ((float4*)params) + NROWS;

    if (i >= NG) {                      // pad rows: always culled (e'=f'=BIG)
        if (sub == 0) {
            cullw[i] = make_float4(0.f, 0.f, 3.0e38f, 3.0e38f);
            rowsw[3*i+0] = make_float4(0.f,0.f,0.f,0.f);
            rowsw[3*i+1] = make_float4(0.f,0.f,0.f,0.f);
            rowsw[3*i+2] = make_float4(0.f,0.f,0.f,0.f);
        }
        return;
    }

    const float tz = s_tz[i];

    // Partial rank over this lane's chunk of the 179 float4 groups.
    const float4* t4 = (const float4*)s_tz;
    int rank = 0;
    const int jj0 = sub * 45;
    const int jj1 = (sub == 3) ? 179 : (jj0 + 45);
    for (int jj = jj0; jj < jj1; ++jj) {
        float4 v = t4[jj];
        int j = 4*jj;
        rank += (v.x < tz) || (v.x == tz && (j+0) < i);
        rank += (v.y < tz) || (v.y == tz && (j+1) < i);
        rank += (v.z < tz) || (v.z == tz && (j+2) < i);
        rank += (v.w < tz) || (v.w == tz && (j+3) < i);
    }
    rank += __shfl_xor(rank, 1);
    rank += __shfl_xor(rank, 2);        // all 4 quad lanes now hold full rank
    if (sub != 0) return;

    float m0 = means[i*3+0], m1 = means[i*3+1];
    float qw = quats[i*4+0], qx = quats[i*4+1], qy = quats[i*4+2], qz = quats[i*4+3];
    float qn = rsqrtf(qw*qw + qx*qx + qy*qy + qz*qz);
    qw*=qn; qx*=qn; qy*=qn; qz*=qn;
    float sx = scales[i*3+0], sy = scales[i*3+1], sz = scales[i*3+2];
    float s0 = sx*sx, s1 = sy*sy, s2 = sz*sz;
    float R00 = 1.f-2.f*(qy*qy+qz*qz), R01 = 2.f*(qx*qy-qw*qz), R02 = 2.f*(qx*qz+qw*qy);
    float R10 = 2.f*(qx*qy+qw*qz),     R11 = 1.f-2.f*(qx*qx+qz*qz), R12 = 2.f*(qy*qz-qw*qx);
    float R20 = 2.f*(qx*qz-qw*qy),     R21 = 2.f*(qy*qz+qw*qx),     R22 = 1.f-2.f*(qx*qx+qy*qy);
    float S00 = R00*R00*s0 + R01*R01*s1 + R02*R02*s2;
    float S01 = R00*R10*s0 + R01*R11*s1 + R02*R12*s2;
    float S02 = R00*R20*s0 + R01*R21*s1 + R02*R22*s2;
    float S11 = R10*R10*s0 + R11*R11*s1 + R12*R12*s2;
    float S12 = R10*R20*s0 + R11*R21*s1 + R12*R22*s2;
    float S22 = R20*R20*s0 + R21*R21*s1 + R22*R22*s2;
    float inv = 1.f/tz;
    float mx = FOCALF*m0*inv + 0.5f*WW;
    float my = FOCALF*m1*inv + 0.5f*HH;
    float j0 = FOCALF*inv;
    float j2 = -FOCALF*m0*inv*inv;
    float j5 = -FOCALF*m1*inv*inv;
    float a = j0*j0*S00 + 2.f*j0*j2*S02 + j2*j2*S22 + EPS2D_F;
    float b = j0*(j0*S01 + j2*S12) + j5*(j0*S02 + j2*S22);
    float c = j0*j0*S11 + 2.f*j0*j5*S12 + j5*j5*S22 + EPS2D_F;
    float det = a*c - b*b;
    float idet = 1.f/det;
    float hA = 0.5f*c*idet*LOG2E_F;      // positive conic terms (log2-scaled)
    float Bc = -b*idet*LOG2E_F;
    float hC = 0.5f*a*idet*LOG2E_F;
    float e  = hC - Bc*Bc/(4.f*hA);      // min over dx of sigma' = e*dy^2
    float f  = hA - Bc*Bc/(4.f*hC);      // min over dy of sigma' = f*dx^2
    float op = 1.f/(1.f+__expf(-opacities[i]));
    float K  = log2f(op);                // folded into exponent
    float thr = log2f(255.f) + K;        // cull iff bound > thr
    // normalized cull fields (thr>0 for all real inputs; guard: thr<=0 ->
    // never box-culled, per-pixel alpha clamp preserves exactness)
    float ep = (thr > 0.f) ? e/thr : 0.f;
    float fp = (thr > 0.f) ? f/thr : 0.f;
    float cr = 1.f/(1.f+__expf(-rgbs[i*3+0]));
    float cg = 1.f/(1.f+__expf(-rgbs[i*3+1]));
    float cb = 1.f/(1.f+__expf(-rgbs[i*3+2]));

    cullw[rank]     = make_float4(mx, my, ep, fp);
    rowsw[3*rank+0] = make_float4(mx, my, -hA, -Bc);
    rowsw[3*rank+1] = make_float4(-hC, K, cr, cg);
    rowsw[3*rank+2] = make_float4(cb, 0.f, 0.f, 0.f);
}

// Kernel 2: compositing, 2048 blocks = 256 tiles x 8 depth slices; block = 4
// waves = 4 sub-segments (23 rows). __launch_bounds__(256,8): all 8 blocks/CU
// co-resident (round-9 win). Ballot PRE-PASS now loads ONE float4 (normalized
// cull row) per lane (round-10); hit-only __ffsll loop with distance-2
// register pipeline (round-5); register-only early break; per-slice any-hit
// flag skips empty-slice stores (round-7).
__global__ __launch_bounds__(256, 8) void gs_composite(
    const float* __restrict__ params, float4* __restrict__ qpart,
    int* __restrict__ flags)
{
    __shared__ float4 part[4][4][64];       // [wave][row k][tx] = 16 KB
    __shared__ int s_any[4];
    const int tx = threadIdx.x;             // 0..63
    const int wv = __builtin_amdgcn_readfirstlane((int)threadIdx.y);
    const int tile = blockIdx.x >> 3;
    const int qtr  = blockIdx.x & 7;
    const int x0 = (tile & 15) * 16;
    const int y0 = (tile >> 4) * 16;
    const float px   = (float)(x0 + (tx & 15)) + 0.5f;
    const float yb   = (float)(y0 + ((tx >> 4) << 2)) + 0.5f;   // row-group base
    const float xc   = (float)x0 + 8.0f;    // box center, half-span 7.5
    const float ycen = (float)y0 + 8.0f;
    const int n0 = (qtr*4 + wv) * SEG;      // wave's sub-segment start

    const float4* cull = (const float4*)params;
    const float4* p4   = ((const float4*)params) + NROWS;

    // Pre-pass: lane l cull-tests row n0+l with a single float4 load.
    unsigned long long mask;
    {
        bool h = false;
        if (tx < SEG) {
            float4 cu = cull[n0 + tx];      // [mx,my,e',f']
            float dymin = fmaxf(fabsf(ycen - cu.y) - 7.5f, 0.f);
            float dxmin = fmaxf(fabsf(xc   - cu.x) - 7.5f, 0.f);
            h = !(fmaxf(cu.z*dymin*dymin, cu.w*dxmin*dxmin) > 1.0f);
        }
        mask = __ballot(h);                 // uniform across the wave
    }
    if (tx == 0) s_any[wv] = (mask != 0ull);

    float T0=1.f,r0=0.f,g0=0.f,bl0=0.f;
    float T1=1.f,r1=0.f,g1=0.f,bl1=0.f;
    float T2=1.f,r2=0.f,g2=0.f,bl2=0.f;
    float T3=1.f,r3=0.f,g3=0.f,bl3=0.f;

    // Hit-only main loop, distance-2 register pipeline through the mask.
    int ra = -1, rb = -1;
    float4 A0,A1,A2,B0,B1,B2;
    if (mask) { ra = n0 + (__ffsll(mask)-1); mask &= mask-1;
                A0=p4[3*ra]; A1=p4[3*ra+1]; A2=p4[3*ra+2]; }
    if (mask) { rb = n0 + (__ffsll(mask)-1); mask &= mask-1;
                B0=p4[3*rb]; B1=p4[3*rb+1]; B2=p4[3*rb+2]; }
    while (ra >= 0) {
        float4 C0,C1,C2; int rc = -1;
        if (mask) { rc = n0 + (__ffsll(mask)-1); mask &= mask-1;
                    C0=p4[3*rc]; C1=p4[3*rc+1]; C2=p4[3*rc+2]; }

        float dy0 = yb - A0.y;
        float dy1 = dy0 + 1.f, dy2 = dy0 + 2.f, dy3 = dy0 + 3.f;
        float dx  = px - A0.x;
        float axx = fmaf(A0.z*dx, dx, A1.y);    // A2n*dx^2 + K
        float bdx = A0.w*dx;

        float sg0 = fmaf(bdx, dy0, fmaf(A1.x*dy0, dy0, axx));
        float al0 = __builtin_amdgcn_exp2f(sg0);
        al0 = (al0 < ALPHA_MIN_F) ? 0.f : al0;
        float w0 = T0*al0; r0 += w0*A1.z; g0 += w0*A1.w; bl0 += w0*A2.x; T0 -= w0;

        float sg1 = fmaf(bdx, dy1, fmaf(A1.x*dy1, dy1, axx));
        float al1 = __builtin_amdgcn_exp2f(sg1);
        al1 = (al1 < ALPHA_MIN_F) ? 0.f : al1;
        float w1 = T1*al1; r1 += w1*A1.z; g1 += w1*A1.w; bl1 += w1*A2.x; T1 -= w1;

        float sg2 = fmaf(bdx, dy2, fmaf(A1.x*dy2, dy2, axx));
        float al2 = __builtin_amdgcn_exp2f(sg2);
        al2 = (al2 < ALPHA_MIN_F) ? 0.f : al2;
        float w2 = T2*al2; r2 += w2*A1.z; g2 += w2*A1.w; bl2 += w2*A2.x; T2 -= w2;

        float sg3 = fmaf(bdx, dy3, fmaf(A1.x*dy3, dy3, axx));
        float al3 = __builtin_amdgcn_exp2f(sg3);
        al3 = (al3 < ALPHA_MIN_F) ? 0.f : al3;
        float w3 = T3*al3; r3 += w3*A1.z; g3 += w3*A1.w; bl3 += w3*A2.x; T3 -= w3;

        // register-only early break (local T bounds true T from above)
        float tmax = fmaxf(fmaxf(T0,T1), fmaxf(T2,T3));
        if (__ballot(tmax > T_EPS) == 0ull) break;

        A0=B0; A1=B1; A2=B2; ra=rb;
        B0=C0; B1=C1; B2=C2; rb=rc;
    }

    part[wv][0][tx] = make_float4(r0,g0,bl0,T0);
    part[wv][1][tx] = make_float4(r1,g1,bl1,T1);
    part[wv][2][tx] = make_float4(r2,g2,bl2,T2);
    part[wv][3][tx] = make_float4(r3,g3,bl3,T3);
    __syncthreads();

    const int nz = s_any[0] | s_any[1] | s_any[2] | s_any[3];   // block-uniform
    if (wv == 0 && tx == 0) flags[blockIdx.x] = nz;             // poison-safe
    if (nz) {   // wave k reduces pixel-row k of each thread's bundle, in order
        const int k = wv;
        float R=0.f,G=0.f,B=0.f,T=1.f;
        #pragma unroll
        for (int s = 0; s < 4; ++s) {
            float4 v = part[s][k][tx];
            R += T*v.x; G += T*v.y; B += T*v.z; T *= v.w;
        }
        const int y = y0 + ((tx >> 4) << 2) + k;
        const int x = x0 + (tx & 15);
        qpart[qtr*NPX + y*WW + x] = make_float4(R,G,B,T);
    }
}

// Kernel 3: fold the flagged depth-slice partials in order. Block = tile so
// the slice-flag branches are block-uniform; empty slices are exact
// identities and are skipped (bit-identical result).
__global__ __launch_bounds__(256) void gs_combine(
    const int* __restrict__ flags, const float4* __restrict__ qpart,
    float* __restrict__ out)
{
    const int tile = blockIdx.x;
    const int t = threadIdx.x;              // 0..255 = pixel-in-tile
    const int x0 = (tile & 15) * 16;
    const int y0 = (tile >> 4) * 16;
    const int y = y0 + (t >> 4);
    const int x = x0 + (t & 15);
    const int px = y*WW + x;
    float R=0.f, G=0.f, B=0.f, T=1.f;
    #pragma unroll
    for (int q = 0; q < NQTR; ++q) {
        if (flags[tile*NQTR + q]) {         // block-uniform
            float4 p = qpart[q*NPX + px];
            R += T*p.x; G += T*p.y; B += T*p.z; T *= p.w;
        }
    }
    out[px*3+0] = R;
    out[px*3+1] = G;
    out[px*3+2] = B;
}

extern "C" void kernel_launch(void* const* d_in, const int* in_sizes, int n_in,
                              void* d_out, int out_size, void* d_ws, size_t ws_size,
                              hipStream_t stream) {
    // d_in: 0=coords (unused by reference), 1=means, 2=quats, 3=scales, 4=opacities, 5=rgbs
    const float* means  = (const float*)d_in[1];
    const float* quats  = (const float*)d_in[2];
    const float* scales = (const float*)d_in[3];
    const float* opac   = (const float*)d_in[4];
    const float* rgbs   = (const float*)d_in[5];

    char* ws = (char*)d_ws;
    float*  params = (float*)ws;                    // cull 12 KB + rows 36 KB
    int*    flags  = (int*)(ws + (48<<10));         // 2048 ints = 8 KB
    float4* qpart  = (float4*)(ws + (64<<10));      // 8*65536*16 B = 8 MB

    gs_prep<<<3, 1024, 0, stream>>>(means, quats, scales, opac, rgbs, params);
    gs_composite<<<256*NQTR, dim3(64,4), 0, stream>>>(params, qpart, flags);
    gs_combine<<<256, 256, 0, stream>>>(flags, qpart, (float*)d_out);
}